// Round 5
// baseline (791.325 us; speedup 1.0000x reference)
//
#include <hip/hip_runtime.h>

#define N_NODES 100000
#define N_EDGES 1600000
#define D_IN    128
#define D_OUT   64

#define XT_STRIDE 260           // gemm LDS pad (proven)
#define NBUCKETS 1563           // ceil(100000/64) 64-row buckets
#define NBW 782                 // packed u16 words = ceil(NBUCKETS/2)
#define G 392                   // scatter/count blocks = 8*49 (XCD-chunked)
#define SLICE 4096              // edges per count/scatter block (16 tiles of 256)
#define M_FLAT (NBUCKETS * G)   // 612,696 (bucket-major count matrix)
#define SCANA_BLOCKS 599        // ceil(M_FLAT/1024)
typedef unsigned long long ull;
typedef unsigned int uint;

// ---------------------------------------------------------------------------
// Kernel A: support = X @ W (fp32). Register-tiled LDS GEMM. (unchanged)
// ---------------------------------------------------------------------------
__global__ __launch_bounds__(256) void gcn_gemm(
    const float* __restrict__ x,        // [N, 128]
    const float* __restrict__ w,        // [128, 64]
    float* __restrict__ support)        // [N, 64]
{
    __shared__ float wl[D_IN * D_OUT];      // 32 KB
    __shared__ float xT[32 * XT_STRIDE];    // 33.3 KB

    const int t  = threadIdx.x;
    const int tx = t & 7;
    const int ty = t >> 3;
    const long row0 = (long)blockIdx.x * 256;

    {
        const float4* wf  = (const float4*)w;
        float4*       wlf = (float4*)wl;
#pragma unroll
        for (int j = 0; j < 8; ++j)
            wlf[t + 256 * j] = wf[t + 256 * j];
    }

    float acc[8][8];
#pragma unroll
    for (int i = 0; i < 8; ++i)
#pragma unroll
        for (int j = 0; j < 8; ++j)
            acc[i][j] = 0.f;

    for (int kc = 0; kc < 4; ++kc) {
        const int k0 = kc * 32;
        __syncthreads();

        const int kk = tx * 4;
#pragma unroll
        for (int it = 0; it < 8; ++it) {
            const int  rg   = it * 32 + ty;
            const long grow = row0 + rg;
            float4 v = make_float4(0.f, 0.f, 0.f, 0.f);
            if (grow < N_NODES)
                v = *(const float4*)&x[grow * D_IN + k0 + kk];
            xT[(kk + 0) * XT_STRIDE + rg] = v.x;
            xT[(kk + 1) * XT_STRIDE + rg] = v.y;
            xT[(kk + 2) * XT_STRIDE + rg] = v.z;
            xT[(kk + 3) * XT_STRIDE + rg] = v.w;
        }
        __syncthreads();

#pragma unroll 8
        for (int k = 0; k < 32; ++k) {
            const float4 a0 = *(const float4*)&xT[k * XT_STRIDE + ty * 8];
            const float4 a1 = *(const float4*)&xT[k * XT_STRIDE + ty * 8 + 4];
            const float4 b0 = *(const float4*)&wl[(k0 + k) * D_OUT + tx * 8];
            const float4 b1 = *(const float4*)&wl[(k0 + k) * D_OUT + tx * 8 + 4];
            const float av[8] = {a0.x, a0.y, a0.z, a0.w, a1.x, a1.y, a1.z, a1.w};
            const float bv[8] = {b0.x, b0.y, b0.z, b0.w, b1.x, b1.y, b1.z, b1.w};
#pragma unroll
            for (int i = 0; i < 8; ++i)
#pragma unroll
                for (int j = 0; j < 8; ++j)
                    acc[i][j] = fmaf(av[i], bv[j], acc[i][j]);
        }
    }

#pragma unroll
    for (int i = 0; i < 8; ++i) {
        const long r = row0 + ty * 8 + i;
        if (r < N_NODES) {
            float4 o0 = make_float4(acc[i][0], acc[i][1], acc[i][2], acc[i][3]);
            float4 o1 = make_float4(acc[i][4], acc[i][5], acc[i][6], acc[i][7]);
            *(float4*)&support[r * D_OUT + tx * 8]     = o0;
            *(float4*)&support[r * D_OUT + tx * 8 + 4] = o1;
        }
    }
}

// ---------------------------------------------------------------------------
// Bucket-level counting sort (64-row buckets). Round-4 evidence: the row-
// exact CSR middle (9 dispatches) cost ~210us while its only consumer needs
// edges merely GROUPED -- a 64-row group fits a 16KB LDS accumulator.
//
// k_cnt: block b (XCD-chunked id) histograms its 4096-edge slice into a
// packed-u16 LDS hist over 1563 buckets, dumps counts to bucket-major
// S[bucket*G + b] (u32). All entries written -> no memset.
// ---------------------------------------------------------------------------
__global__ __launch_bounds__(256) void k_cnt(
    const int* __restrict__ rows, uint* __restrict__ S)
{
    __shared__ uint hist[NBW];
    const int t = threadIdx.x;
    const int b = (blockIdx.x & 7) * 49 + (blockIdx.x >> 3);  // chunked XCD swz
    for (int i = t; i < NBW; i += 256) hist[i] = 0u;
    __syncthreads();

    const int base = b * SLICE;
#pragma unroll 4
    for (int s2 = 0; s2 < 16; ++s2) {
        const int e = base + s2 * 256 + t;
        if (e < N_EDGES) {
            const uint bk = (uint)rows[e] >> 6;
            atomicAdd(&hist[bk >> 1], 1u << ((bk & 1) * 16));
        }
    }
    __syncthreads();

    for (int i = t; i < NBUCKETS; i += 256)
        S[(size_t)i * G + b] = (hist[i >> 1] >> ((i & 1) * 16)) & 0xffffu;
}

// ---------------------------------------------------------------------------
// Flat exclusive scan of the bucket-major count matrix (612,696 u32).
// Bucket-major flattening means scanned S[bucket*G+b] IS the global scatter
// base for (bucket, block) -- no separate per-row offset machinery.
// ---------------------------------------------------------------------------
__global__ __launch_bounds__(256) void k_scanA(
    uint* __restrict__ S, uint* __restrict__ bsum)
{
    __shared__ uint s[256];
    const int t = threadIdx.x;
    const size_t base = (size_t)blockIdx.x * 1024 + (size_t)t * 4;
    uint4 v = make_uint4(0u, 0u, 0u, 0u);
    if (base < M_FLAT) v = *(const uint4*)&S[base];   // M_FLAT%4==0 -> all-or-none
    const uint tsum = v.x + v.y + v.z + v.w;
    s[t] = tsum;
    __syncthreads();
#pragma unroll
    for (int off = 1; off < 256; off <<= 1) {
        const uint add = (t >= off) ? s[t - off] : 0u;
        __syncthreads();
        s[t] += add;
        __syncthreads();
    }
    const uint eb = s[t] - tsum;
    if (t == 255) bsum[blockIdx.x] = s[255];
    if (base < M_FLAT) {
        uint4 o;
        o.x = eb; o.y = eb + v.x; o.z = o.y + v.y; o.w = o.z + v.z;
        *(uint4*)&S[base] = o;
    }
}

__global__ __launch_bounds__(1024) void k_scanB(uint* __restrict__ bsum)
{
    __shared__ uint s[1024];
    const int t = threadIdx.x;
    const uint v = (t < SCANA_BLOCKS) ? bsum[t] : 0u;
    s[t] = v;
    __syncthreads();
#pragma unroll
    for (int off = 1; off < 1024; off <<= 1) {
        const uint add = (t >= off) ? s[t - off] : 0u;
        __syncthreads();
        s[t] += add;
        __syncthreads();
    }
    if (t < SCANA_BLOCKS) bsum[t] = s[t] - v;
}

__global__ __launch_bounds__(256) void k_scanC(
    uint* __restrict__ S, const uint* __restrict__ bsum)
{
    const uint add = bsum[blockIdx.x];
    const size_t base = (size_t)blockIdx.x * 1024 + (size_t)threadIdx.x * 4;
    if (base < M_FLAT) {
        uint4 v = *(const uint4*)&S[base];
        v.x += add; v.y += add; v.z += add; v.w += add;
        *(uint4*)&S[base] = v;
    }
}

// ---------------------------------------------------------------------------
// k_scatter: block b reloads its slice; LDS u32 cursor per bucket seeded
// from scanned S column; pos = LDS atomicAdd. Per-(block,bucket) ranges are
// contiguous and adjacent blocks share an XCD (chunked swz) -> pair lines
// assemble in one L2. Packed u64: val:32 | r_local:6 (bits 17..22) | col:17.
// ---------------------------------------------------------------------------
__global__ __launch_bounds__(256) void k_scatter(
    const int* __restrict__ rows, const int* __restrict__ cols,
    const float* __restrict__ vals, const uint* __restrict__ S,
    ull* __restrict__ pairs)
{
    __shared__ uint cur[NBUCKETS];          // 6.25 KB
    const int t = threadIdx.x;
    const int b = (blockIdx.x & 7) * 49 + (blockIdx.x >> 3);
    for (int i = t; i < NBUCKETS; i += 256) cur[i] = S[(size_t)i * G + b];
    __syncthreads();

    const int base = b * SLICE;
#pragma unroll 4
    for (int s2 = 0; s2 < 16; ++s2) {
        const int e = base + s2 * 256 + t;
        if (e < N_EDGES) {
            const uint r  = (uint)rows[e];
            const uint bk = r >> 6;
            const uint rl = r & 63u;
            const uint pos = atomicAdd(&cur[bk], 1u);
            pairs[pos] = ((ull)__float_as_uint(vals[e]) << 32)
                       | (rl << 17) | (uint)cols[e];
        }
    }
}

// ---------------------------------------------------------------------------
// k_agg: one block per 64-row bucket. 16KB LDS fp32 accumulator; stream the
// bucket's contiguous pair segment (staged to LDS), 8-deep gather unroll
// (same MLP as round-4 rowsum), ds_add_f32 accumulate (lane=col -> 2-way
// bank alias = free), fused PReLU store. 18KB LDS -> 8 blocks/CU -> 32 waves.
// ---------------------------------------------------------------------------
__global__ __launch_bounds__(256) void k_agg(
    const uint* __restrict__ S, const ull* __restrict__ pairs,
    const float* __restrict__ support, const float* __restrict__ prelu_a,
    float* __restrict__ out)
{
    __shared__ float acc[64 * D_OUT];       // 16 KB
    __shared__ ull sld[256];                // 2 KB staging
    const int t = threadIdx.x, w = t >> 6, lane = t & 63;
    const int k = blockIdx.x;

    for (int i = t; i < 64 * D_OUT; i += 256) acc[i] = 0.f;
    const int beg = (int)S[(size_t)k * G];
    const int end = (k == NBUCKETS - 1) ? N_EDGES : (int)S[(size_t)(k + 1) * G];
    __syncthreads();

    for (int c = beg; c < end; c += 256) {
        const int m = min(256, end - c);
        if (t < m) sld[t] = pairs[c + t];
        __syncthreads();
        const int w0 = w * 64;
        const int mw = min(64, max(0, m - w0));
        int i = 0;
        for (; i + 8 <= mw; i += 8) {
            ull p[8];
#pragma unroll
            for (int u = 0; u < 8; ++u) p[u] = sld[w0 + i + u];
            float sv[8];
#pragma unroll
            for (int u = 0; u < 8; ++u)
                sv[u] = support[(size_t)((uint)p[u] & 0x1ffffu) * D_OUT + lane];
#pragma unroll
            for (int u = 0; u < 8; ++u) {
                const uint rl = ((uint)p[u] >> 17) & 63u;
                atomicAdd(&acc[rl * D_OUT + lane],
                          __uint_as_float((uint)(p[u] >> 32)) * sv[u]);
            }
        }
        for (; i < mw; ++i) {
            const ull p = sld[w0 + i];
            const float sv = support[(size_t)((uint)p & 0x1ffffu) * D_OUT + lane];
            const uint rl = ((uint)p >> 17) & 63u;
            atomicAdd(&acc[rl * D_OUT + lane],
                      __uint_as_float((uint)(p >> 32)) * sv);
        }
        __syncthreads();                    // sld reuse + acc settle
    }

    const float a = prelu_a[0];
    const long r0 = (long)k * 64;
    for (int i = w; i < 64; i += 4) {
        const long r = r0 + i;
        if (r < N_NODES) {
            const float v = acc[i * D_OUT + lane];
            out[r * D_OUT + lane] = v > 0.f ? v : a * v;
        }
    }
}

// ---------------------------------------------------------------------------
extern "C" void kernel_launch(void* const* d_in, const int* in_sizes, int n_in,
                              void* d_out, int out_size, void* d_ws, size_t ws_size,
                              hipStream_t stream) {
    const float* x    = (const float*)d_in[0];
    const int*   rows = (const int*)d_in[1];
    const int*   cols = (const int*)d_in[2];
    const float* vals = (const float*)d_in[3];
    const float* w    = (const float*)d_in[4];
    const float* pa   = (const float*)d_in[5];

    float* out     = (float*)d_out;                    // [N*64] PReLU output
    float* support = out + (size_t)N_NODES * D_OUT;    // [N*64] support (tuple elem 1)

    // workspace layout (~15.3 MiB)
    uint* S     = (uint*)d_ws;                 // 613,376 u32 (M_FLAT padded to 599*1024)
    uint* bsumA = S + (size_t)SCANA_BLOCKS * 1024;   // 1024 u32
    ull*  pairs = (ull*)(bsumA + 1024);        // byte off (613376+1024)*4 = 2,457,600 (8B ok)

    gcn_gemm <<<(N_NODES + 255) / 256, 256, 0, stream>>>(x, w, support);
    k_cnt    <<<G, 256, 0, stream>>>(rows, S);
    k_scanA  <<<SCANA_BLOCKS, 256, 0, stream>>>(S, bsumA);
    k_scanB  <<<1, 1024, 0, stream>>>(bsumA);
    k_scanC  <<<SCANA_BLOCKS, 256, 0, stream>>>(S, bsumA);
    k_scatter<<<G, 256, 0, stream>>>(rows, cols, vals, S, pairs);
    k_agg    <<<NBUCKETS, 256, 0, stream>>>(S, pairs, support, pa, out);
}

// Round 6
// 264.880 us; speedup vs baseline: 2.9875x; 2.9875x over previous
//
#include <hip/hip_runtime.h>

#define N_NODES 100000
#define N_EDGES 1600000
#define D_IN    128
#define D_OUT   64

#define XT_STRIDE 260           // gemm LDS pad (proven)
#define NBUCKETS 1563           // ceil(100000/64) 64-row buckets
#define NBW 782                 // packed u16 words = ceil(NBUCKETS/2)
#define G 392                   // scatter/count blocks = 8*49 (XCD-chunked)
#define SLICE 4096              // edges per count/scatter block
#define M_FLAT (NBUCKETS * G)   // 612,696 (bucket-major count matrix)
#define SCANA_BLOCKS 599        // ceil(M_FLAT/1024)
typedef unsigned long long ull;
typedef unsigned int uint;

// ---------------------------------------------------------------------------
// Kernel A: support = X @ W (fp32). Register-tiled LDS GEMM. (proven)
// ---------------------------------------------------------------------------
__global__ __launch_bounds__(256) void gcn_gemm(
    const float* __restrict__ x,        // [N, 128]
    const float* __restrict__ w,        // [128, 64]
    float* __restrict__ support)        // [N, 64]
{
    __shared__ float wl[D_IN * D_OUT];      // 32 KB
    __shared__ float xT[32 * XT_STRIDE];    // 33.3 KB

    const int t  = threadIdx.x;
    const int tx = t & 7;
    const int ty = t >> 3;
    const long row0 = (long)blockIdx.x * 256;

    {
        const float4* wf  = (const float4*)w;
        float4*       wlf = (float4*)wl;
#pragma unroll
        for (int j = 0; j < 8; ++j)
            wlf[t + 256 * j] = wf[t + 256 * j];
    }

    float acc[8][8];
#pragma unroll
    for (int i = 0; i < 8; ++i)
#pragma unroll
        for (int j = 0; j < 8; ++j)
            acc[i][j] = 0.f;

    for (int kc = 0; kc < 4; ++kc) {
        const int k0 = kc * 32;
        __syncthreads();

        const int kk = tx * 4;
#pragma unroll
        for (int it = 0; it < 8; ++it) {
            const int  rg   = it * 32 + ty;
            const long grow = row0 + rg;
            float4 v = make_float4(0.f, 0.f, 0.f, 0.f);
            if (grow < N_NODES)
                v = *(const float4*)&x[grow * D_IN + k0 + kk];
            xT[(kk + 0) * XT_STRIDE + rg] = v.x;
            xT[(kk + 1) * XT_STRIDE + rg] = v.y;
            xT[(kk + 2) * XT_STRIDE + rg] = v.z;
            xT[(kk + 3) * XT_STRIDE + rg] = v.w;
        }
        __syncthreads();

#pragma unroll 8
        for (int k = 0; k < 32; ++k) {
            const float4 a0 = *(const float4*)&xT[k * XT_STRIDE + ty * 8];
            const float4 a1 = *(const float4*)&xT[k * XT_STRIDE + ty * 8 + 4];
            const float4 b0 = *(const float4*)&wl[(k0 + k) * D_OUT + tx * 8];
            const float4 b1 = *(const float4*)&wl[(k0 + k) * D_OUT + tx * 8 + 4];
            const float av[8] = {a0.x, a0.y, a0.z, a0.w, a1.x, a1.y, a1.z, a1.w};
            const float bv[8] = {b0.x, b0.y, b0.z, b0.w, b1.x, b1.y, b1.z, b1.w};
#pragma unroll
            for (int i = 0; i < 8; ++i)
#pragma unroll
                for (int j = 0; j < 8; ++j)
                    acc[i][j] = fmaf(av[i], bv[j], acc[i][j]);
        }
    }

#pragma unroll
    for (int i = 0; i < 8; ++i) {
        const long r = row0 + ty * 8 + i;
        if (r < N_NODES) {
            float4 o0 = make_float4(acc[i][0], acc[i][1], acc[i][2], acc[i][3]);
            float4 o1 = make_float4(acc[i][4], acc[i][5], acc[i][6], acc[i][7]);
            *(float4*)&support[r * D_OUT + tx * 8]     = o0;
            *(float4*)&support[r * D_OUT + tx * 8 + 4] = o1;
        }
    }
}

// ---------------------------------------------------------------------------
// Bucket counting sort middle (round-5 proven-correct, cheap).
// k_cnt: block b histograms its 4096-edge slice into packed-u16 LDS hist
// over 1563 buckets (bucket = row>>6), dumps counts bucket-major S[i*G+b].
// ---------------------------------------------------------------------------
__global__ __launch_bounds__(256) void k_cnt(
    const int* __restrict__ rows, uint* __restrict__ S)
{
    __shared__ uint hist[NBW];
    const int t = threadIdx.x;
    const int b = (blockIdx.x & 7) * 49 + (blockIdx.x >> 3);  // chunked XCD swz
    for (int i = t; i < NBW; i += 256) hist[i] = 0u;
    __syncthreads();

    const int base = b * SLICE;
#pragma unroll 4
    for (int s2 = 0; s2 < 16; ++s2) {
        const int e = base + s2 * 256 + t;
        if (e < N_EDGES) {
            const uint bk = (uint)rows[e] >> 6;
            atomicAdd(&hist[bk >> 1], 1u << ((bk & 1) * 16));
        }
    }
    __syncthreads();

    for (int i = t; i < NBUCKETS; i += 256)
        S[(size_t)i * G + b] = (hist[i >> 1] >> ((i & 1) * 16)) & 0xffffu;
}

// ---------------------------------------------------------------------------
// Flat exclusive scan of the bucket-major count matrix. Scanned S[i*G+b] IS
// the global scatter base for (bucket i, block b).
// ---------------------------------------------------------------------------
__global__ __launch_bounds__(256) void k_scanA(
    uint* __restrict__ S, uint* __restrict__ bsum)
{
    __shared__ uint s[256];
    const int t = threadIdx.x;
    const size_t base = (size_t)blockIdx.x * 1024 + (size_t)t * 4;
    uint4 v = make_uint4(0u, 0u, 0u, 0u);
    if (base < M_FLAT) v = *(const uint4*)&S[base];   // M_FLAT%4==0
    const uint tsum = v.x + v.y + v.z + v.w;
    s[t] = tsum;
    __syncthreads();
#pragma unroll
    for (int off = 1; off < 256; off <<= 1) {
        const uint add = (t >= off) ? s[t - off] : 0u;
        __syncthreads();
        s[t] += add;
        __syncthreads();
    }
    const uint eb = s[t] - tsum;
    if (t == 255) bsum[blockIdx.x] = s[255];
    if (base < M_FLAT) {
        uint4 o;
        o.x = eb; o.y = eb + v.x; o.z = o.y + v.y; o.w = o.z + v.z;
        *(uint4*)&S[base] = o;
    }
}

__global__ __launch_bounds__(1024) void k_scanB(uint* __restrict__ bsum)
{
    __shared__ uint s[1024];
    const int t = threadIdx.x;
    const uint v = (t < SCANA_BLOCKS) ? bsum[t] : 0u;
    s[t] = v;
    __syncthreads();
#pragma unroll
    for (int off = 1; off < 1024; off <<= 1) {
        const uint add = (t >= off) ? s[t - off] : 0u;
        __syncthreads();
        s[t] += add;
        __syncthreads();
    }
    if (t < SCANA_BLOCKS) bsum[t] = s[t] - v;
}

__global__ __launch_bounds__(256) void k_scanC(
    uint* __restrict__ S, const uint* __restrict__ bsum)
{
    const uint add = bsum[blockIdx.x];
    const size_t base = (size_t)blockIdx.x * 1024 + (size_t)threadIdx.x * 4;
    if (base < M_FLAT) {
        uint4 v = *(const uint4*)&S[base];
        v.x += add; v.y += add; v.z += add; v.w += add;
        *(uint4*)&S[base] = v;
    }
}

// ---------------------------------------------------------------------------
// k_scatter: block b reloads its slice; LDS u32 cursor per bucket (native
// ds_add), pos = bucket-sorted position. Packed u64: val:32 | rl:6@17 | col:17.
// ---------------------------------------------------------------------------
__global__ __launch_bounds__(256) void k_scatter(
    const int* __restrict__ rows, const int* __restrict__ cols,
    const float* __restrict__ vals, const uint* __restrict__ S,
    ull* __restrict__ pairs)
{
    __shared__ uint cur[NBUCKETS];          // 6.25 KB
    const int t = threadIdx.x;
    const int b = (blockIdx.x & 7) * 49 + (blockIdx.x >> 3);
    for (int i = t; i < NBUCKETS; i += 256) cur[i] = S[(size_t)i * G + b];
    __syncthreads();

    const int base = b * SLICE;
#pragma unroll 4
    for (int s2 = 0; s2 < 16; ++s2) {
        const int e = base + s2 * 256 + t;
        if (e < N_EDGES) {
            const uint r  = (uint)rows[e];
            const uint bk = r >> 6;
            const uint rl = r & 63u;
            const uint pos = atomicAdd(&cur[bk], 1u);
            pairs[pos] = ((ull)__float_as_uint(vals[e]) << 32)
                       | (rl << 17) | (uint)cols[e];
        }
    }
}

// ---------------------------------------------------------------------------
// k_bsort (NEW, replaces the failed fp-LDS-atomic k_agg): one block per
// 64-row bucket. INTEGER LDS hist (native ds_add_u32) over the bucket's
// contiguous segment -> 64-wide scan -> re-scatter row-sorted into pairs2;
// emits offsets[row]/counts[row] for the proven k_rowsum.
// (Round-5 evidence: atomicAdd on SHARED FLOAT is a CAS loop -> k_agg at
//  609us with HBM 4.3% / VALU 3.1%. No fp atomics anywhere now.)
// ---------------------------------------------------------------------------
__global__ __launch_bounds__(256) void k_bsort(
    const uint* __restrict__ S, const ull* __restrict__ pairs,
    ull* __restrict__ pairs2, int* __restrict__ offsets,
    int* __restrict__ counts)
{
    __shared__ uint h[64], ex[64], cur[64];
    const int k = blockIdx.x;
    const int t = threadIdx.x;
    const int beg = (int)S[(size_t)k * G];
    const int end = (k == NBUCKETS - 1) ? N_EDGES : (int)S[(size_t)(k + 1) * G];

    if (t < 64) h[t] = 0u;
    __syncthreads();

    for (int i = beg + t; i < end; i += 256)
        atomicAdd(&h[((uint)pairs[i] >> 17) & 63u], 1u);
    __syncthreads();

    if (t < 64) ex[t] = h[t];
    __syncthreads();
#pragma unroll
    for (int off = 1; off < 64; off <<= 1) {
        const uint add = (t >= off && t < 64) ? ex[t - off] : 0u;
        __syncthreads();
        if (t < 64) ex[t] += add;
        __syncthreads();
    }
    if (t < 64) {
        const uint e0 = ex[t] - h[t];           // exclusive
        cur[t] = (uint)beg + e0;
        const int row = k * 64 + t;
        if (row < N_NODES) {
            counts[row]  = (int)h[t];
            offsets[row] = beg + (int)e0;
        }
    }
    __syncthreads();

    for (int i = beg + t; i < end; i += 256) {
        const ull p = pairs[i];
        const uint rl = ((uint)p >> 17) & 63u;
        const uint pos = atomicAdd(&cur[rl], 1u);
        pairs2[pos] = p;
    }
}

// ---------------------------------------------------------------------------
// Segmented row sum + fused PReLU (round-4 proven: 63us, 3.4 TB/s).
// One wave per row, lane = column, 8-deep gather unroll.
// ---------------------------------------------------------------------------
__global__ __launch_bounds__(256) void k_rowsum(
    const int* __restrict__ offsets, const int* __restrict__ counts,
    const ull* __restrict__ pairs, const float* __restrict__ support,
    const float* __restrict__ prelu_a, float* __restrict__ out)
{
    const int lane = threadIdx.x & 63;
    const int row  = blockIdx.x * 4 + (threadIdx.x >> 6);  // grid exact: N%4==0

    const int start = offsets[row];
    const int deg   = counts[row];

    float acc = 0.f;
    int j = 0;
    for (; j + 8 <= deg; j += 8) {
        ull p[8];
#pragma unroll
        for (int u = 0; u < 8; ++u) p[u] = pairs[start + j + u];
        float s[8];
#pragma unroll
        for (int u = 0; u < 8; ++u)
            s[u] = support[(size_t)((uint)p[u] & 0x1ffffu) * D_OUT + lane];
#pragma unroll
        for (int u = 0; u < 8; ++u)
            acc = fmaf(__uint_as_float((uint)(p[u] >> 32)), s[u], acc);
    }
    for (; j + 4 <= deg; j += 4) {
        ull p[4];
#pragma unroll
        for (int u = 0; u < 4; ++u) p[u] = pairs[start + j + u];
        float s[4];
#pragma unroll
        for (int u = 0; u < 4; ++u)
            s[u] = support[(size_t)((uint)p[u] & 0x1ffffu) * D_OUT + lane];
#pragma unroll
        for (int u = 0; u < 4; ++u)
            acc = fmaf(__uint_as_float((uint)(p[u] >> 32)), s[u], acc);
    }
    for (; j < deg; ++j) {
        const ull p = pairs[start + j];
        const float s = support[(size_t)((uint)p & 0x1ffffu) * D_OUT + lane];
        acc = fmaf(__uint_as_float((uint)(p >> 32)), s, acc);
    }

    const float a = prelu_a[0];
    out[(size_t)row * D_OUT + lane] = acc > 0.f ? acc : a * acc;
}

// ---------------------------------------------------------------------------
extern "C" void kernel_launch(void* const* d_in, const int* in_sizes, int n_in,
                              void* d_out, int out_size, void* d_ws, size_t ws_size,
                              hipStream_t stream) {
    const float* x    = (const float*)d_in[0];
    const int*   rows = (const int*)d_in[1];
    const int*   cols = (const int*)d_in[2];
    const float* vals = (const float*)d_in[3];
    const float* w    = (const float*)d_in[4];
    const float* pa   = (const float*)d_in[5];

    float* out     = (float*)d_out;                    // [N*64] PReLU output
    float* support = out + (size_t)N_NODES * D_OUT;    // [N*64] support (tuple elem 1)

    // workspace layout (~29 MiB)
    uint* S       = (uint*)d_ws;                         // 599*1024 u32
    uint* bsumA   = S + (size_t)SCANA_BLOCKS * 1024;     // 1024 u32
    int*  offsets = (int*)(bsumA + 1024);                // 100032
    int*  counts  = offsets + 100032;                    // 100032
    // byte offset: (613376+1024+100032+100032)*4 = 3,257,856 (8B-aligned)
    ull*  pairs   = (ull*)(counts + 100032);             // 1.6M x 8B
    ull*  pairs2  = pairs + N_EDGES;                     // 1.6M x 8B

    gcn_gemm <<<(N_NODES + 255) / 256, 256, 0, stream>>>(x, w, support);
    k_cnt    <<<G, 256, 0, stream>>>(rows, S);
    k_scanA  <<<SCANA_BLOCKS, 256, 0, stream>>>(S, bsumA);
    k_scanB  <<<1, 1024, 0, stream>>>(bsumA);
    k_scanC  <<<SCANA_BLOCKS, 256, 0, stream>>>(S, bsumA);
    k_scatter<<<G, 256, 0, stream>>>(rows, cols, vals, S, pairs);
    k_bsort  <<<NBUCKETS, 256, 0, stream>>>(S, pairs, pairs2, offsets, counts);
    k_rowsum <<<N_NODES / 4, 256, 0, stream>>>(offsets, counts, pairs2, support, pa, out);
}

// Round 7
// 251.472 us; speedup vs baseline: 3.1468x; 1.0533x over previous
//
#include <hip/hip_runtime.h>

#define N_NODES 100000
#define N_EDGES 1600000
#define D_IN    128
#define D_OUT   64

#define XT_STRIDE 260           // gemm LDS pad (proven)
#define NBUCKETS 1563           // ceil(100000/64) 64-row buckets
#define NBW 782                 // packed u16 words = ceil(NBUCKETS/2)
#define G 392                   // scatter/count blocks = 8*49 (XCD-chunked)
#define SLICE 4096              // edges per count/scatter block
#define M_FLAT (NBUCKETS * G)   // 612,696 (bucket-major count matrix)
#define SCANA_BLOCKS 599        // ceil(M_FLAT/1024)
#define GEMM_BLOCKS 391         // ceil(N_NODES/256)
#define CAP 2048                // LDS bucket-segment capacity (expected max ~1150)
typedef unsigned long long ull;
typedef unsigned int uint;

// ---------------------------------------------------------------------------
// Fused: support = X @ W (blocks 0..390, proven gemm) || bucket count
// (blocks 391..782, proven k_cnt on hist aliased over gemm's LDS).
// Independent work; cnt (~6us) hides fully under gemm's VALU time, and one
// launch+gap is saved.
// ---------------------------------------------------------------------------
__global__ __launch_bounds__(256) void k_gemm_cnt(
    const float* __restrict__ x,        // [N, 128]
    const float* __restrict__ w,        // [128, 64]
    float* __restrict__ support,        // [N, 64]
    const int* __restrict__ rows,
    uint* __restrict__ S)
{
    __shared__ float wl[D_IN * D_OUT];      // 32 KB (cnt aliases hist here)
    __shared__ float xT[32 * XT_STRIDE];    // 33.3 KB

    const int t = threadIdx.x;

    if (blockIdx.x >= GEMM_BLOCKS) {
        // ---- count path (k_cnt, proven round 5/6) ----
        uint* hist = (uint*)wl;             // NBW=782 u32 = 3.1 KB
        const int bid = blockIdx.x - GEMM_BLOCKS;
        const int b = (bid & 7) * 49 + (bid >> 3);  // chunked XCD swz
        for (int i = t; i < NBW; i += 256) hist[i] = 0u;
        __syncthreads();

        const int base = b * SLICE;
#pragma unroll 4
        for (int s2 = 0; s2 < 16; ++s2) {
            const int e = base + s2 * 256 + t;
            if (e < N_EDGES) {
                const uint bk = (uint)rows[e] >> 6;
                atomicAdd(&hist[bk >> 1], 1u << ((bk & 1) * 16));
            }
        }
        __syncthreads();

        for (int i = t; i < NBUCKETS; i += 256)
            S[(size_t)i * G + b] = (hist[i >> 1] >> ((i & 1) * 16)) & 0xffffu;
        return;
    }

    // ---- gemm path (proven since round 0) ----
    const int tx = t & 7;
    const int ty = t >> 3;
    const long row0 = (long)blockIdx.x * 256;

    {
        const float4* wf  = (const float4*)w;
        float4*       wlf = (float4*)wl;
#pragma unroll
        for (int j = 0; j < 8; ++j)
            wlf[t + 256 * j] = wf[t + 256 * j];
    }

    float acc[8][8];
#pragma unroll
    for (int i = 0; i < 8; ++i)
#pragma unroll
        for (int j = 0; j < 8; ++j)
            acc[i][j] = 0.f;

    for (int kc = 0; kc < 4; ++kc) {
        const int k0 = kc * 32;
        __syncthreads();

        const int kk = tx * 4;
#pragma unroll
        for (int it = 0; it < 8; ++it) {
            const int  rg   = it * 32 + ty;
            const long grow = row0 + rg;
            float4 v = make_float4(0.f, 0.f, 0.f, 0.f);
            if (grow < N_NODES)
                v = *(const float4*)&x[grow * D_IN + k0 + kk];
            xT[(kk + 0) * XT_STRIDE + rg] = v.x;
            xT[(kk + 1) * XT_STRIDE + rg] = v.y;
            xT[(kk + 2) * XT_STRIDE + rg] = v.z;
            xT[(kk + 3) * XT_STRIDE + rg] = v.w;
        }
        __syncthreads();

#pragma unroll 8
        for (int k = 0; k < 32; ++k) {
            const float4 a0 = *(const float4*)&xT[k * XT_STRIDE + ty * 8];
            const float4 a1 = *(const float4*)&xT[k * XT_STRIDE + ty * 8 + 4];
            const float4 b0 = *(const float4*)&wl[(k0 + k) * D_OUT + tx * 8];
            const float4 b1 = *(const float4*)&wl[(k0 + k) * D_OUT + tx * 8 + 4];
            const float av[8] = {a0.x, a0.y, a0.z, a0.w, a1.x, a1.y, a1.z, a1.w};
            const float bv[8] = {b0.x, b0.y, b0.z, b0.w, b1.x, b1.y, b1.z, b1.w};
#pragma unroll
            for (int i = 0; i < 8; ++i)
#pragma unroll
                for (int j = 0; j < 8; ++j)
                    acc[i][j] = fmaf(av[i], bv[j], acc[i][j]);
        }
    }

#pragma unroll
    for (int i = 0; i < 8; ++i) {
        const long r = row0 + ty * 8 + i;
        if (r < N_NODES) {
            float4 o0 = make_float4(acc[i][0], acc[i][1], acc[i][2], acc[i][3]);
            float4 o1 = make_float4(acc[i][4], acc[i][5], acc[i][6], acc[i][7]);
            *(float4*)&support[r * D_OUT + tx * 8]     = o0;
            *(float4*)&support[r * D_OUT + tx * 8 + 4] = o1;
        }
    }
}

// ---------------------------------------------------------------------------
// k_scanA: per-1024-chunk exclusive scan of bucket-major S; bsum gets chunk
// totals. Consumers add bsum[flat>>10] inline -> NO scanC pass needed.
// ---------------------------------------------------------------------------
__global__ __launch_bounds__(256) void k_scanA(
    uint* __restrict__ S, uint* __restrict__ bsum)
{
    __shared__ uint s[256];
    const int t = threadIdx.x;
    const size_t base = (size_t)blockIdx.x * 1024 + (size_t)t * 4;
    uint4 v = make_uint4(0u, 0u, 0u, 0u);
    if (base < M_FLAT) v = *(const uint4*)&S[base];   // M_FLAT%4==0
    const uint tsum = v.x + v.y + v.z + v.w;
    s[t] = tsum;
    __syncthreads();
#pragma unroll
    for (int off = 1; off < 256; off <<= 1) {
        const uint add = (t >= off) ? s[t - off] : 0u;
        __syncthreads();
        s[t] += add;
        __syncthreads();
    }
    const uint eb = s[t] - tsum;
    if (t == 255) bsum[blockIdx.x] = s[255];
    if (base < M_FLAT) {
        uint4 o;
        o.x = eb; o.y = eb + v.x; o.z = o.y + v.y; o.w = o.z + v.z;
        *(uint4*)&S[base] = o;
    }
}

__global__ __launch_bounds__(1024) void k_scanB(uint* __restrict__ bsum)
{
    __shared__ uint s[1024];
    const int t = threadIdx.x;
    const uint v = (t < SCANA_BLOCKS) ? bsum[t] : 0u;
    s[t] = v;
    __syncthreads();
#pragma unroll
    for (int off = 1; off < 1024; off <<= 1) {
        const uint add = (t >= off) ? s[t - off] : 0u;
        __syncthreads();
        s[t] += add;
        __syncthreads();
    }
    if (t < SCANA_BLOCKS) bsum[t] = s[t] - v;
}

// ---------------------------------------------------------------------------
// k_scatter: block b reloads its slice; LDS u32 cursor per bucket seeded
// from S[i*G+b] + bsum[(i*G+b)>>10] (scanC folded in here). pos = native
// LDS atomicAdd. Writes bucket-sorted pairs: val:32 | rl:6@17 | col:17.
// ---------------------------------------------------------------------------
__global__ __launch_bounds__(256) void k_scatter(
    const int* __restrict__ rows, const int* __restrict__ cols,
    const float* __restrict__ vals, const uint* __restrict__ S,
    const uint* __restrict__ bsum, ull* __restrict__ pairs)
{
    __shared__ uint cur[NBUCKETS];          // 6.25 KB
    __shared__ uint bs[SCANA_BLOCKS + 1];   // 2.4 KB
    const int t = threadIdx.x;
    const int b = (blockIdx.x & 7) * 49 + (blockIdx.x >> 3);

    for (int i = t; i < SCANA_BLOCKS; i += 256) bs[i] = bsum[i];
    __syncthreads();
    for (int i = t; i < NBUCKETS; i += 256) {
        const size_t f = (size_t)i * G + b;
        cur[i] = S[f] + bs[f >> 10];
    }
    __syncthreads();

    const int base = b * SLICE;
#pragma unroll 4
    for (int s2 = 0; s2 < 16; ++s2) {
        const int e = base + s2 * 256 + t;
        if (e < N_EDGES) {
            const uint r  = (uint)rows[e];
            const uint bk = r >> 6;
            const uint rl = r & 63u;
            const uint pos = atomicAdd(&cur[bk], 1u);
            pairs[pos] = ((ull)__float_as_uint(vals[e]) << 32)
                       | (rl << 17) | (uint)cols[e];
        }
    }
}

// ---------------------------------------------------------------------------
// k_bucket (fuses round-6 bsort + rowsum): one block per 64-row bucket.
// Stage the bucket's contiguous segment in LDS, integer hist (ds_add_u32) +
// 64-scan + reorder ENTIRELY in LDS (pairs2/offsets/counts global traffic
// eliminated: ~38 MB), then 4 waves x 16 rows run the proven lane=col
// 8-deep gather rowsum + fused PReLU. No fp atomics anywhere (round-5
// lesson). CAP=2048 >> expected max segment ~1150; correct fallback kept.
// ---------------------------------------------------------------------------
__global__ __launch_bounds__(256) void k_bucket(
    const uint* __restrict__ S, const uint* __restrict__ bsum,
    const ull* __restrict__ pairs, const float* __restrict__ support,
    const float* __restrict__ prelu_a, float* __restrict__ out)
{
    __shared__ ull seg[CAP];                // 16 KB
    __shared__ ull srt[CAP];                // 16 KB
    __shared__ uint h[64], ex[64], rowoff[64], cur[64];
    const int k = blockIdx.x;
    const int t = threadIdx.x, w = t >> 6, lane = t & 63;

    const size_t f0 = (size_t)k * G;
    const int beg = (int)(S[f0] + bsum[f0 >> 10]);
    int end;
    if (k == NBUCKETS - 1) end = N_EDGES;
    else {
        const size_t f1 = f0 + G;
        end = (int)(S[f1] + bsum[f1 >> 10]);
    }
    const int n = end - beg;
    const float a = prelu_a[0];

    if (t < 64) h[t] = 0u;
    __syncthreads();

    if (n <= CAP) {
        for (int i = t; i < n; i += 256) {
            const ull p = pairs[beg + i];
            seg[i] = p;
            atomicAdd(&h[((uint)p >> 17) & 63u], 1u);
        }
        __syncthreads();

        if (t < 64) ex[t] = h[t];
        __syncthreads();
#pragma unroll
        for (int off = 1; off < 64; off <<= 1) {
            const uint add = (t >= off && t < 64) ? ex[t - off] : 0u;
            __syncthreads();
            if (t < 64) ex[t] += add;
            __syncthreads();
        }
        if (t < 64) {
            rowoff[t] = ex[t] - h[t];
            cur[t]    = rowoff[t];
        }
        __syncthreads();

        for (int i = t; i < n; i += 256) {
            const ull p = seg[i];
            const uint pos = atomicAdd(&cur[((uint)p >> 17) & 63u], 1u);
            srt[pos] = p;
        }
        __syncthreads();

        // rowsum: wave w owns rows w*16 .. w*16+15 of this bucket
        for (int q = 0; q < 16; ++q) {
            const int rl  = w * 16 + q;
            const long row = (long)k * 64 + rl;
            if (row >= N_NODES) break;
            const int st  = (int)rowoff[rl];
            const int deg = (int)h[rl];

            float acc = 0.f;
            int j = 0;
            for (; j + 8 <= deg; j += 8) {
                ull p[8];
#pragma unroll
                for (int u = 0; u < 8; ++u) p[u] = srt[st + j + u];
                float sv[8];
#pragma unroll
                for (int u = 0; u < 8; ++u)
                    sv[u] = support[(size_t)((uint)p[u] & 0x1ffffu) * D_OUT + lane];
#pragma unroll
                for (int u = 0; u < 8; ++u)
                    acc = fmaf(__uint_as_float((uint)(p[u] >> 32)), sv[u], acc);
            }
            for (; j + 4 <= deg; j += 4) {
                ull p[4];
#pragma unroll
                for (int u = 0; u < 4; ++u) p[u] = srt[st + j + u];
                float sv[4];
#pragma unroll
                for (int u = 0; u < 4; ++u)
                    sv[u] = support[(size_t)((uint)p[u] & 0x1ffffu) * D_OUT + lane];
#pragma unroll
                for (int u = 0; u < 4; ++u)
                    acc = fmaf(__uint_as_float((uint)(p[u] >> 32)), sv[u], acc);
            }
            for (; j < deg; ++j) {
                const ull p = srt[st + j];
                acc = fmaf(__uint_as_float((uint)(p >> 32)),
                           support[(size_t)((uint)p & 0x1ffffu) * D_OUT + lane], acc);
            }
            out[row * D_OUT + lane] = acc > 0.f ? acc : a * acc;
        }
    } else {
        // never expected (n <= ~1150); correct slow path
        for (int q = 0; q < 16; ++q) {
            const int rl  = w * 16 + q;
            const long row = (long)k * 64 + rl;
            if (row >= N_NODES) break;
            float acc = 0.f;
            for (int i = 0; i < n; ++i) {
                const ull p = pairs[beg + i];
                if ((((uint)p >> 17) & 63u) == (uint)rl)
                    acc = fmaf(__uint_as_float((uint)(p >> 32)),
                               support[(size_t)((uint)p & 0x1ffffu) * D_OUT + lane],
                               acc);
            }
            out[row * D_OUT + lane] = acc > 0.f ? acc : a * acc;
        }
    }
}

// ---------------------------------------------------------------------------
extern "C" void kernel_launch(void* const* d_in, const int* in_sizes, int n_in,
                              void* d_out, int out_size, void* d_ws, size_t ws_size,
                              hipStream_t stream) {
    const float* x    = (const float*)d_in[0];
    const int*   rows = (const int*)d_in[1];
    const int*   cols = (const int*)d_in[2];
    const float* vals = (const float*)d_in[3];
    const float* w    = (const float*)d_in[4];
    const float* pa   = (const float*)d_in[5];

    float* out     = (float*)d_out;                    // [N*64] PReLU output
    float* support = out + (size_t)N_NODES * D_OUT;    // [N*64] support (tuple elem 1)

    // workspace layout (~15.3 MiB)
    uint* S     = (uint*)d_ws;                         // 599*1024 u32
    uint* bsum  = S + (size_t)SCANA_BLOCKS * 1024;     // 1024 u32
    // byte offset: (613376+1024)*4 = 2,457,600 (8B-aligned)
    ull*  pairs = (ull*)(bsum + 1024);                 // 1.6M x 8B

    k_gemm_cnt<<<GEMM_BLOCKS + G, 256, 0, stream>>>(x, w, support, rows, S);
    k_scanA   <<<SCANA_BLOCKS, 256, 0, stream>>>(S, bsum);
    k_scanB   <<<1, 1024, 0, stream>>>(bsum);
    k_scatter <<<G, 256, 0, stream>>>(rows, cols, vals, S, bsum, pairs);
    k_bucket  <<<NBUCKETS, 256, 0, stream>>>(S, bsum, pairs, support, pa, out);
}

// Round 8
// 242.912 us; speedup vs baseline: 3.2577x; 1.0352x over previous
//
#include <hip/hip_runtime.h>

#define N_NODES 100000
#define N_EDGES 1600000
#define D_IN    128
#define D_OUT   64

#define XT_STRIDE 260           // gemm LDS pad (proven)
#define NBUCKETS 1563           // ceil(100000/64) 64-row buckets
#define NBW 782                 // packed u16 words = ceil(NBUCKETS/2)
#define G 392                   // scatter/count blocks = 8*49 (XCD-chunked)
#define SLICE 4096              // edges per count/scatter block
#define M_FLAT (NBUCKETS * G)   // 612,696 (bucket-major count matrix)
#define SCANA_BLOCKS 599        // ceil(M_FLAT/1024)
#define GEMM_BLOCKS 391         // ceil(N_NODES/256)
#define CAP 2048                // LDS bucket-segment capacity (expected max ~1150)
typedef unsigned long long ull;
typedef unsigned int uint;

// ---------------------------------------------------------------------------
// Fused: support = X @ W (blocks 0..390, proven gemm) || bucket count
// (blocks 391..782, proven k_cnt on hist aliased over gemm's LDS).
// ---------------------------------------------------------------------------
__global__ __launch_bounds__(256) void k_gemm_cnt(
    const float* __restrict__ x,        // [N, 128]
    const float* __restrict__ w,        // [128, 64]
    float* __restrict__ support,        // [N, 64]
    const int* __restrict__ rows,
    uint* __restrict__ S)
{
    __shared__ float wl[D_IN * D_OUT];      // 32 KB (cnt aliases hist here)
    __shared__ float xT[32 * XT_STRIDE];    // 33.3 KB

    const int t = threadIdx.x;

    if (blockIdx.x >= GEMM_BLOCKS) {
        // ---- count path ----
        uint* hist = (uint*)wl;             // NBW=782 u32 = 3.1 KB
        const int bid = blockIdx.x - GEMM_BLOCKS;
        const int b = (bid & 7) * 49 + (bid >> 3);  // chunked XCD swz
        for (int i = t; i < NBW; i += 256) hist[i] = 0u;
        __syncthreads();

        const int base = b * SLICE;
#pragma unroll 4
        for (int s2 = 0; s2 < 16; ++s2) {
            const int e = base + s2 * 256 + t;
            if (e < N_EDGES) {
                const uint bk = (uint)rows[e] >> 6;
                atomicAdd(&hist[bk >> 1], 1u << ((bk & 1) * 16));
            }
        }
        __syncthreads();

        for (int i = t; i < NBUCKETS; i += 256)
            S[(size_t)i * G + b] = (hist[i >> 1] >> ((i & 1) * 16)) & 0xffffu;
        return;
    }

    // ---- gemm path (proven since round 0) ----
    const int tx = t & 7;
    const int ty = t >> 3;
    const long row0 = (long)blockIdx.x * 256;

    {
        const float4* wf  = (const float4*)w;
        float4*       wlf = (float4*)wl;
#pragma unroll
        for (int j = 0; j < 8; ++j)
            wlf[t + 256 * j] = wf[t + 256 * j];
    }

    float acc[8][8];
#pragma unroll
    for (int i = 0; i < 8; ++i)
#pragma unroll
        for (int j = 0; j < 8; ++j)
            acc[i][j] = 0.f;

    for (int kc = 0; kc < 4; ++kc) {
        const int k0 = kc * 32;
        __syncthreads();

        const int kk = tx * 4;
#pragma unroll
        for (int it = 0; it < 8; ++it) {
            const int  rg   = it * 32 + ty;
            const long grow = row0 + rg;
            float4 v = make_float4(0.f, 0.f, 0.f, 0.f);
            if (grow < N_NODES)
                v = *(const float4*)&x[grow * D_IN + k0 + kk];
            xT[(kk + 0) * XT_STRIDE + rg] = v.x;
            xT[(kk + 1) * XT_STRIDE + rg] = v.y;
            xT[(kk + 2) * XT_STRIDE + rg] = v.z;
            xT[(kk + 3) * XT_STRIDE + rg] = v.w;
        }
        __syncthreads();

#pragma unroll 8
        for (int k = 0; k < 32; ++k) {
            const float4 a0 = *(const float4*)&xT[k * XT_STRIDE + ty * 8];
            const float4 a1 = *(const float4*)&xT[k * XT_STRIDE + ty * 8 + 4];
            const float4 b0 = *(const float4*)&wl[(k0 + k) * D_OUT + tx * 8];
            const float4 b1 = *(const float4*)&wl[(k0 + k) * D_OUT + tx * 8 + 4];
            const float av[8] = {a0.x, a0.y, a0.z, a0.w, a1.x, a1.y, a1.z, a1.w};
            const float bv[8] = {b0.x, b0.y, b0.z, b0.w, b1.x, b1.y, b1.z, b1.w};
#pragma unroll
            for (int i = 0; i < 8; ++i)
#pragma unroll
                for (int j = 0; j < 8; ++j)
                    acc[i][j] = fmaf(av[i], bv[j], acc[i][j]);
        }
    }

#pragma unroll
    for (int i = 0; i < 8; ++i) {
        const long r = row0 + ty * 8 + i;
        if (r < N_NODES) {
            float4 o0 = make_float4(acc[i][0], acc[i][1], acc[i][2], acc[i][3]);
            float4 o1 = make_float4(acc[i][4], acc[i][5], acc[i][6], acc[i][7]);
            *(float4*)&support[r * D_OUT + tx * 8]     = o0;
            *(float4*)&support[r * D_OUT + tx * 8 + 4] = o1;
        }
    }
}

// ---------------------------------------------------------------------------
// k_scanA: per-1024-chunk exclusive scan of bucket-major S; bsum gets chunk
// totals. Consumers add bsum[flat>>10] inline -> NO scanC pass needed.
// ---------------------------------------------------------------------------
__global__ __launch_bounds__(256) void k_scanA(
    uint* __restrict__ S, uint* __restrict__ bsum)
{
    __shared__ uint s[256];
    const int t = threadIdx.x;
    const size_t base = (size_t)blockIdx.x * 1024 + (size_t)t * 4;
    uint4 v = make_uint4(0u, 0u, 0u, 0u);
    if (base < M_FLAT) v = *(const uint4*)&S[base];   // M_FLAT%4==0
    const uint tsum = v.x + v.y + v.z + v.w;
    s[t] = tsum;
    __syncthreads();
#pragma unroll
    for (int off = 1; off < 256; off <<= 1) {
        const uint add = (t >= off) ? s[t - off] : 0u;
        __syncthreads();
        s[t] += add;
        __syncthreads();
    }
    const uint eb = s[t] - tsum;
    if (t == 255) bsum[blockIdx.x] = s[255];
    if (base < M_FLAT) {
        uint4 o;
        o.x = eb; o.y = eb + v.x; o.z = o.y + v.y; o.w = o.z + v.z;
        *(uint4*)&S[base] = o;
    }
}

__global__ __launch_bounds__(1024) void k_scanB(uint* __restrict__ bsum)
{
    __shared__ uint s[1024];
    const int t = threadIdx.x;
    const uint v = (t < SCANA_BLOCKS) ? bsum[t] : 0u;
    s[t] = v;
    __syncthreads();
#pragma unroll
    for (int off = 1; off < 1024; off <<= 1) {
        const uint add = (t >= off) ? s[t - off] : 0u;
        __syncthreads();
        s[t] += add;
        __syncthreads();
    }
    if (t < SCANA_BLOCKS) bsum[t] = s[t] - v;
}

// ---------------------------------------------------------------------------
// k_scatter: block b reloads its slice; LDS u32 cursor per bucket seeded
// from S[i*G+b] + bsum[(i*G+b)>>10]. Writes bucket-sorted pairs:
// val:32 | rl:6@17 | col:17.
// ---------------------------------------------------------------------------
__global__ __launch_bounds__(256) void k_scatter(
    const int* __restrict__ rows, const int* __restrict__ cols,
    const float* __restrict__ vals, const uint* __restrict__ S,
    const uint* __restrict__ bsum, ull* __restrict__ pairs)
{
    __shared__ uint cur[NBUCKETS];          // 6.25 KB
    __shared__ uint bs[SCANA_BLOCKS + 1];   // 2.4 KB
    const int t = threadIdx.x;
    const int b = (blockIdx.x & 7) * 49 + (blockIdx.x >> 3);

    for (int i = t; i < SCANA_BLOCKS; i += 256) bs[i] = bsum[i];
    __syncthreads();
    for (int i = t; i < NBUCKETS; i += 256) {
        const size_t f = (size_t)i * G + b;
        cur[i] = S[f] + bs[f >> 10];
    }
    __syncthreads();

    const int base = b * SLICE;
#pragma unroll 4
    for (int s2 = 0; s2 < 16; ++s2) {
        const int e = base + s2 * 256 + t;
        if (e < N_EDGES) {
            const uint r  = (uint)rows[e];
            const uint bk = r >> 6;
            const uint rl = r & 63u;
            const uint pos = atomicAdd(&cur[bk], 1u);
            pairs[pos] = ((ull)__float_as_uint(vals[e]) << 32)
                       | (rl << 17) | (uint)cols[e];
        }
    }
}

// ---------------------------------------------------------------------------
// k_bucket: one block per 64-row bucket.
// (Round-7 evidence: 33.8KB LDS (seg+srt) capped occupancy at 30.7% ->
//  gather BW fell to 2.86 TB/s vs rowsum's 3.42 at 70% occ. The seg staging
//  buffer existed only to avoid a second global read of an ~8KB CONTIGUOUS,
//  L2-HOT segment. Deleted: two-pass global read, LDS = srt only (17.3KB)
//  -> 8 blocks/CU -> full 32-wave occupancy.)
// Pass 1: read segment, integer LDS hist (ds_add_u32). 64-scan. Pass 2:
// re-read (L2-hot), scatter row-sorted into srt. Then 4 waves x 16 rows run
// the proven lane=col 8-deep gather rowsum + fused PReLU. No fp atomics.
// ---------------------------------------------------------------------------
__global__ __launch_bounds__(256) void k_bucket(
    const uint* __restrict__ S, const uint* __restrict__ bsum,
    const ull* __restrict__ pairs, const float* __restrict__ support,
    const float* __restrict__ prelu_a, float* __restrict__ out)
{
    __shared__ ull srt[CAP];                // 16 KB
    __shared__ uint h[64], ex[64], rowoff[64], cur[64];
    const int k = blockIdx.x;
    const int t = threadIdx.x, w = t >> 6, lane = t & 63;

    const size_t f0 = (size_t)k * G;
    const int beg = (int)(S[f0] + bsum[f0 >> 10]);
    int end;
    if (k == NBUCKETS - 1) end = N_EDGES;
    else {
        const size_t f1 = f0 + G;
        end = (int)(S[f1] + bsum[f1 >> 10]);
    }
    const int n = end - beg;
    const float a = prelu_a[0];

    if (t < 64) h[t] = 0u;
    __syncthreads();

    if (n <= CAP) {
        // pass 1: hist (segment is contiguous; this read warms L2)
        for (int i = t; i < n; i += 256)
            atomicAdd(&h[((uint)pairs[beg + i] >> 17) & 63u], 1u);
        __syncthreads();

        if (t < 64) ex[t] = h[t];
        __syncthreads();
#pragma unroll
        for (int off = 1; off < 64; off <<= 1) {
            const uint add = (t >= off && t < 64) ? ex[t - off] : 0u;
            __syncthreads();
            if (t < 64) ex[t] += add;
            __syncthreads();
        }
        if (t < 64) {
            rowoff[t] = ex[t] - h[t];
            cur[t]    = rowoff[t];
        }
        __syncthreads();

        // pass 2: re-read (L2-hot) + row-sort into LDS
        for (int i = t; i < n; i += 256) {
            const ull p = pairs[beg + i];
            const uint pos = atomicAdd(&cur[((uint)p >> 17) & 63u], 1u);
            srt[pos] = p;
        }
        __syncthreads();

        // rowsum: wave w owns rows w*16 .. w*16+15 of this bucket
        for (int q = 0; q < 16; ++q) {
            const int rl  = w * 16 + q;
            const long row = (long)k * 64 + rl;
            if (row >= N_NODES) break;
            const int st  = (int)rowoff[rl];
            const int deg = (int)h[rl];

            float acc = 0.f;
            int j = 0;
            for (; j + 8 <= deg; j += 8) {
                ull p[8];
#pragma unroll
                for (int u = 0; u < 8; ++u) p[u] = srt[st + j + u];
                float sv[8];
#pragma unroll
                for (int u = 0; u < 8; ++u)
                    sv[u] = support[(size_t)((uint)p[u] & 0x1ffffu) * D_OUT + lane];
#pragma unroll
                for (int u = 0; u < 8; ++u)
                    acc = fmaf(__uint_as_float((uint)(p[u] >> 32)), sv[u], acc);
            }
            for (; j + 4 <= deg; j += 4) {
                ull p[4];
#pragma unroll
                for (int u = 0; u < 4; ++u) p[u] = srt[st + j + u];
                float sv[4];
#pragma unroll
                for (int u = 0; u < 4; ++u)
                    sv[u] = support[(size_t)((uint)p[u] & 0x1ffffu) * D_OUT + lane];
#pragma unroll
                for (int u = 0; u < 4; ++u)
                    acc = fmaf(__uint_as_float((uint)(p[u] >> 32)), sv[u], acc);
            }
            for (; j < deg; ++j) {
                const ull p = srt[st + j];
                acc = fmaf(__uint_as_float((uint)(p >> 32)),
                           support[(size_t)((uint)p & 0x1ffffu) * D_OUT + lane], acc);
            }
            out[row * D_OUT + lane] = acc > 0.f ? acc : a * acc;
        }
    } else {
        // never expected (n <= ~1150); correct slow path
        for (int q = 0; q < 16; ++q) {
            const int rl  = w * 16 + q;
            const long row = (long)k * 64 + rl;
            if (row >= N_NODES) break;
            float acc = 0.f;
            for (int i = 0; i < n; ++i) {
                const ull p = pairs[beg + i];
                if ((((uint)p >> 17) & 63u) == (uint)rl)
                    acc = fmaf(__uint_as_float((uint)(p >> 32)),
                               support[(size_t)((uint)p & 0x1ffffu) * D_OUT + lane],
                               acc);
            }
            out[row * D_OUT + lane] = acc > 0.f ? acc : a * acc;
        }
    }
}

// ---------------------------------------------------------------------------
extern "C" void kernel_launch(void* const* d_in, const int* in_sizes, int n_in,
                              void* d_out, int out_size, void* d_ws, size_t ws_size,
                              hipStream_t stream) {
    const float* x    = (const float*)d_in[0];
    const int*   rows = (const int*)d_in[1];
    const int*   cols = (const int*)d_in[2];
    const float* vals = (const float*)d_in[3];
    const float* w    = (const float*)d_in[4];
    const float* pa   = (const float*)d_in[5];

    float* out     = (float*)d_out;                    // [N*64] PReLU output
    float* support = out + (size_t)N_NODES * D_OUT;    // [N*64] support (tuple elem 1)

    // workspace layout (~15.3 MiB)
    uint* S     = (uint*)d_ws;                         // 599*1024 u32
    uint* bsum  = S + (size_t)SCANA_BLOCKS * 1024;     // 1024 u32
    // byte offset: (613376+1024)*4 = 2,457,600 (8B-aligned)
    ull*  pairs = (ull*)(bsum + 1024);                 // 1.6M x 8B

    k_gemm_cnt<<<GEMM_BLOCKS + G, 256, 0, stream>>>(x, w, support, rows, S);
    k_scanA   <<<SCANA_BLOCKS, 256, 0, stream>>>(S, bsum);
    k_scanB   <<<1, 1024, 0, stream>>>(bsum);
    k_scatter <<<G, 256, 0, stream>>>(rows, cols, vals, S, bsum, pairs);
    k_bucket  <<<NBUCKETS, 256, 0, stream>>>(S, bsum, pairs, support, pa, out);
}